// Round 7
// baseline (715.149 us; speedup 1.0000x reference)
//
#include <hip/hip_runtime.h>
#include <hip/hip_bf16.h>

#define NN 50000
#define EE 800000
#define INF 512
#define HH 8
#define DD 64
#define HD 512

typedef unsigned short u16;
typedef u16 u16x4 __attribute__((ext_vector_type(4)));
typedef u16 u16x8 __attribute__((ext_vector_type(8)));
typedef __bf16 bf16x8 __attribute__((ext_vector_type(8)));
typedef float f32x4 __attribute__((ext_vector_type(4)));

__device__ __forceinline__ float bf2f(u16 u) {
    return __uint_as_float(((unsigned)u) << 16);
}
__device__ __forceinline__ u16 f2bf(float f) {
    __hip_bfloat16 h = __float2bfloat16(f);
    return *reinterpret_cast<u16*>(&h);
}

// async global->LDS, 16B per lane; LDS dest = wave-uniform base + lane*16
__device__ __forceinline__ void gload_lds16(const void* g, void* l) {
    __builtin_amdgcn_global_load_lds(
        (const __attribute__((address_space(1))) void*)g,
        (__attribute__((address_space(3))) void*)l, 16, 0, 0);
}

// ---- per-block dtype sniff (identical sampling to the old sniff5 kernel:
// u16s at even indices 0..510 of the input; uniform data -> uniform verdict
// across all blocks). vote: any 4B-aligned LDS scratch. 256-thread blocks.
__device__ __forceinline__ int sniff_region(const u16* __restrict__ p, int* vote) {
    int tid = threadIdx.x;
    if (tid == 0) *vote = 0;
    __syncthreads();
    float v = fabsf(bf2f(p[2 * tid]));
    if (!(v < 1e4f)) atomicAdd(vote, 1);  // huge / inf / NaN -> looks like f32 guts
    __syncthreads();
    int r = (*vote >= 8) ? 1 : 0;
    __syncthreads();  // protect vote slot before caller reuses the LDS
    return r;
}

// ---- prep (fused): [0,2048) convert feat->bf16 | [2048,2176) transpose W_fc/W_res
//      | [2176,2372) zero deg.  Removes 4 standalone launches + flags dependency.
#define PREP_CONV 2048
#define PREP_TR   (PREP_CONV + 128)
#define PREP_ZERO (PREP_TR + 196)

__global__ __launch_bounds__(256) void prep_kernel(const void* __restrict__ feat,
                                                   u16* __restrict__ feat16,
                                                   const void* __restrict__ W_fc,
                                                   const void* __restrict__ W_res,
                                                   u16* __restrict__ Wt,
                                                   int* __restrict__ deg) {
    __shared__ u16 tile[64][65];
    const int bid = blockIdx.x;
    const int tid = threadIdx.x;
    if (bid < PREP_CONV) {
        const int isf32 = sniff_region((const u16*)feat, (int*)&tile[0][0]);
        const int total = NN * INF / 8;  // 8 elems per thread
        for (int i = bid * 256 + tid; i < total; i += PREP_CONV * 256) {
            if (isf32) {
                f32x4 a = ((const f32x4*)feat)[2 * i];
                f32x4 b = ((const f32x4*)feat)[2 * i + 1];
                u16x8 w;
#pragma unroll
                for (int j = 0; j < 4; ++j) { w[j] = f2bf(a[j]); w[4 + j] = f2bf(b[j]); }
                ((u16x8*)feat16)[i] = w;
            } else {
                ((u16x8*)feat16)[i] = ((const u16x8*)feat)[i];
            }
        }
    } else if (bid < PREP_TR) {
        const int w = bid - PREP_CONV;           // 0..127
        const void* in = (w < 64) ? W_fc : W_res;
        u16* out = Wt + ((w < 64) ? 0 : 512 * 512);
        const int tb = w & 63;
        const int isf32 = sniff_region((const u16*)in, (int*)&tile[0][0]);
        int tr = (tb & 7) * 64;   // k tile
        int tc = (tb >> 3) * 64;  // col tile
        for (int idx = tid; idx < 64 * 64; idx += 256) {
            int r = idx >> 6, c = idx & 63;
            int g = (tr + r) * 512 + tc + c;
            tile[r][c] = isf32 ? f2bf(((const float*)in)[g]) : ((const u16*)in)[g];
        }
        __syncthreads();
        for (int idx = tid; idx < 64 * 64; idx += 256) {
            int r = idx >> 6, c = idx & 63;
            out[(tc + r) * 512 + tr + c] = tile[c][r];
        }
    } else {
        int t = (bid - PREP_TR) * 256 + tid;
        if (t < NN) deg[t] = 0;
    }
}

// ---------------- CSR build: count -> scan -> scatter ----------------
__global__ void count_kernel(const int* __restrict__ dst, int* __restrict__ deg) {
    int e = blockIdx.x * 256 + threadIdx.x;
    if (e < EE) atomicAdd(&deg[dst[e]], 1);
}

#define SCAN_CH 49  // 1024 * 49 = 50176 >= NN
__global__ __launch_bounds__(1024) void scan_kernel(const int* __restrict__ deg,
                                                    int* __restrict__ rowptr,
                                                    int* __restrict__ cursor) {
    __shared__ int sums[1024];
    int t = threadIdx.x;
    int base = t * SCAN_CH;
    int s = 0;
    for (int k = 0; k < SCAN_CH; ++k) {
        int i = base + k;
        if (i < NN) s += deg[i];
    }
    sums[t] = s;
    __syncthreads();
    // Hillis-Steele inclusive scan
    for (int off = 1; off < 1024; off <<= 1) {
        int v = (t >= off) ? sums[t - off] : 0;
        __syncthreads();
        sums[t] += v;
        __syncthreads();
    }
    int run = (t == 0) ? 0 : sums[t - 1];
    for (int k = 0; k < SCAN_CH; ++k) {
        int i = base + k;
        if (i < NN) {
            rowptr[i] = run;
            cursor[i] = run;
            run += deg[i];
        }
    }
    if (t == 0) rowptr[NN] = EE;
}

__global__ void scatter_kernel(const int* __restrict__ src, const int* __restrict__ dst,
                               int* __restrict__ cursor, int* __restrict__ csr_src) {
    int e = blockIdx.x * 256 + threadIdx.x;
    if (e < EE) {
        int p = atomicAdd(&cursor[dst[e]], 1);
        csr_src[p] = src[e];
    }
}

// ---- fused GEMM: [N,512]bf16 @ [512,1024] -> ft (bf16) | residual -> out (f32)
//      + el/er epilogue (attn_dot folded in).
// Pure m97 structure: global_load_lds(16B) both operands, 128^2 tile, BK=64,
// single-buffer 32KB LDS -> 5 blocks/CU. XOR chunk swizzle via pre-swizzled
// global source (conflict-free, proven r2). XCD-bijective block swizzle
// (proven: FETCH 402MB -> 63MB).
// el/er: blocks with n0<512 cover 2 COMPLETE heads (D=64 divides the 128-col
// tile), so each (row,head) dot is complete in this block -> computed from the
// f32 accumulators (4 FMA + shfl_xor{1,2,4,8} reduce over the 16 lrow lanes)
// and stored directly. No atomics, no extra ft pass.
#define TM 128
#define TN 128
#define BK 64
#define NT (INF / BK)  // 8
#define NMBLK 392      // 392*128 >= NN, grid 392*8 divisible by 8 XCDs

__global__ __launch_bounds__(256, 5) void gemm_kernel(const u16* __restrict__ Ab,
                                                      const u16* __restrict__ Wt,
                                                      u16* __restrict__ ft,
                                                      float* __restrict__ outf,
                                                      const void* __restrict__ al,
                                                      const void* __restrict__ ar,
                                                      float* __restrict__ el,
                                                      float* __restrict__ er) {
    __shared__ u16 Asm[TM * BK];  // 16KB
    __shared__ u16 Bsm[TN * BK];  // 16KB

    const int bid = blockIdx.x;
    const int r8 = bid & 7;
    const int q = bid >> 3;
    const int m0 = (((q >> 3) << 3) | r8) * TM;
    const int n0 = (q & 7) * TN;
    const int tid = threadIdx.x;
    const int lane = tid & 63;
    const int wave = tid >> 6;
    const int wr = (wave >> 1) * 64;
    const int wc = (wave & 1) * 64;
    const int lrow = lane & 15;
    const int quad = lane >> 4;

    // staging geometry: 1KB group = 8 rows x 128B; lane -> (rg=lane>>3, ch=lane&7)
    const int rg = lane >> 3;
    const int ch = lane & 7;
    const int cs = ch ^ rg;  // pre-swizzled source chunk (row&7 == rg)

    const u16* asrc[4];
    const u16* bsrc[4];
    u16* adst[4];
    u16* bdst[4];
#pragma unroll
    for (int g = 0; g < 4; ++g) {
        int G = wave * 4 + g;
        int r = G * 8 + rg;
        int gr = m0 + r; gr = gr < NN ? gr : NN - 1;   // clamp (dup row harmless)
        asrc[g] = Ab + (size_t)gr * INF + cs * 8;
        bsrc[g] = Wt + (size_t)(n0 + r) * INF + cs * 8;
        adst[g] = Asm + G * 512;
        bdst[g] = Bsm + G * 512;
    }

    f32x4 acc[4][4] = {};

    for (int t = 0; t < NT; ++t) {
        const int k0 = t * BK;
        __syncthreads();  // previous tile's frag reads done before overwrite
#pragma unroll
        for (int g = 0; g < 4; ++g) {
            gload_lds16(asrc[g] + k0, adst[g]);
            gload_lds16(bsrc[g] + k0, bdst[g]);
        }
        __syncthreads();  // vmcnt drain -> tile visible (TLP hides across blocks)

#pragma unroll
        for (int ks = 0; ks < 2; ++ks) {
            bf16x8 af[4], bfr[4];
#pragma unroll
            for (int mi = 0; mi < 4; ++mi) {
                int ar_ = wr + mi * 16 + lrow;
                int sc = (ks * 4 + quad) ^ (ar_ & 7);
                u16x8 tv = *(const u16x8*)(Asm + ar_ * 64 + sc * 8);
                af[mi] = *(bf16x8*)&tv;
            }
#pragma unroll
            for (int ni = 0; ni < 4; ++ni) {
                int br = wc + ni * 16 + lrow;
                int sc = (ks * 4 + quad) ^ (br & 7);
                u16x8 tv = *(const u16x8*)(Bsm + br * 64 + sc * 8);
                bfr[ni] = *(bf16x8*)&tv;
            }
#pragma unroll
            for (int mi = 0; mi < 4; ++mi)
#pragma unroll
                for (int ni = 0; ni < 4; ++ni)
                    acc[mi][ni] = __builtin_amdgcn_mfma_f32_16x16x32_bf16(af[mi], bfr[ni],
                                                                          acc[mi][ni], 0, 0, 0);
        }
    }

    // epilogue: C layout col=lane&15, row=quad*4+reg (m89/m91-verified)
#pragma unroll
    for (int mi = 0; mi < 4; ++mi) {
        int rb = m0 + wr + mi * 16 + quad * 4;
#pragma unroll
        for (int ni = 0; ni < 4; ++ni) {
            int col = n0 + wc + ni * 16 + lrow;
#pragma unroll
            for (int r = 0; r < 4; ++r) {
                int row = rb + r;
                if (row < NN) {
                    float v = acc[mi][ni][r];
                    if (col < HD) ft[row * HD + col] = f2bf(v);
                    else outf[row * HD + (col - HD)] = v;  // residual init of d_out
                }
            }
        }
    }

    // el/er epilogue (only ft-half blocks; per-block uniform branch)
    if (n0 < HD) {
        __syncthreads();  // all waves done reading Asm before vote reuse
        const int fal = sniff_region((const u16*)al, (int*)Asm);
        const int far_ = sniff_region((const u16*)ar, (int*)Asm);
        const int h = (n0 >> 6) + (wc >> 6);  // this wave's head
        float alv[4], arv[4];
#pragma unroll
        for (int ni = 0; ni < 4; ++ni) {
            int idx = h * DD + ni * 16 + lrow;
            alv[ni] = fal ? ((const float*)al)[idx] : bf2f(((const u16*)al)[idx]);
            arv[ni] = far_ ? ((const float*)ar)[idx] : bf2f(((const u16*)ar)[idx]);
        }
#pragma unroll
        for (int mi = 0; mi < 4; ++mi) {
#pragma unroll
            for (int r = 0; r < 4; ++r) {
                float se = 0.0f, sr = 0.0f;
#pragma unroll
                for (int ni = 0; ni < 4; ++ni) {
                    se += acc[mi][ni][r] * alv[ni];
                    sr += acc[mi][ni][r] * arv[ni];
                }
#pragma unroll
                for (int m = 1; m < 16; m <<= 1) {
                    se += __shfl_xor(se, m);
                    sr += __shfl_xor(sr, m);
                }
                int row = m0 + wr + mi * 16 + quad * 4 + r;
                if (lrow == 0 && row < NN) {
                    el[row * HH + h] = se;
                    er[row * HH + h] = sr;
                }
            }
        }
    }
}

// ---- aggregate (gather): 2 waves per dst node; 4-deep static software pipeline ----
// (round-4 verbatim: best measured 141.9us; BW ceiling ~4.1 TB/s for this pattern)
// No-max softmax: scale-invariant; v clamped at 75 as overflow insurance.
// All pipeline slots are named registers (rule #20: no runtime indexing).
__global__ __launch_bounds__(256) void aggregate_kernel(const int* __restrict__ rowptr,
                                                        const int* __restrict__ csr_src,
                                                        const u16* __restrict__ ft,
                                                        const float* __restrict__ el,
                                                        const float* __restrict__ er,
                                                        float* __restrict__ outf) {
    int node = blockIdx.x * 2 + (threadIdx.x >> 7);
    if (node >= NN) return;
    int half = (threadIdx.x >> 6) & 1;
    int lane = threadIdx.x & 63;
    int ebase = half * 256 + lane * 4;  // output element offset within [0,512)
    int head = ebase >> 6;              // = half*4 + (lane>>4)
    int beg = rowptr[node], end = rowptr[node + 1];
    float erd = er[node * HH + head];

    float sden = 0.0f;
    float acc0 = 0.f, acc1 = 0.f, acc2 = 0.f, acc3 = 0.f;

    if (beg < end) {
        const int last = end - 1;
        float elp0, elp1, elp2, elp3;
        u16x4 fp0, fp1, fp2, fp3;
        int sn0, sn1, sn2, sn3;
        // prologue: chunk0 srcs -> fill slots; chunk1 srcs into sn*
        {
            int c0 = csr_src[min(beg + 0, last)];
            int c1 = csr_src[min(beg + 1, last)];
            int c2 = csr_src[min(beg + 2, last)];
            int c3 = csr_src[min(beg + 3, last)];
            elp0 = el[c0 * HH + head]; fp0 = *(const u16x4*)(ft + c0 * HD + ebase);
            elp1 = el[c1 * HH + head]; fp1 = *(const u16x4*)(ft + c1 * HD + ebase);
            elp2 = el[c2 * HH + head]; fp2 = *(const u16x4*)(ft + c2 * HD + ebase);
            elp3 = el[c3 * HH + head]; fp3 = *(const u16x4*)(ft + c3 * HD + ebase);
            sn0 = csr_src[min(beg + 4, last)];
            sn1 = csr_src[min(beg + 5, last)];
            sn2 = csr_src[min(beg + 6, last)];
            sn3 = csr_src[min(beg + 7, last)];
        }
        for (int base = beg; base < end; base += 4) {
#define PROC(K)                                                              \
            {                                                                \
                float elv = elp##K;                                          \
                u16x4 f = fp##K;                                             \
                int s = sn##K;                                               \
                elp##K = el[s * HH + head];                                  \
                fp##K = *(const u16x4*)(ft + s * HD + ebase);                \
                sn##K = csr_src[min(base + 8 + K, last)];                    \
                float v = elv + erd;                                         \
                v = v > 0.0f ? v : 0.2f * v;                                 \
                v = fminf(v, 75.0f);                                         \
                float ex = __expf(v);                                        \
                ex = (base + K < end) ? ex : 0.0f;                           \
                sden += ex;                                                  \
                acc0 += bf2f(f[0]) * ex;                                     \
                acc1 += bf2f(f[1]) * ex;                                     \
                acc2 += bf2f(f[2]) * ex;                                     \
                acc3 += bf2f(f[3]) * ex;                                     \
            }
            PROC(0) PROC(1) PROC(2) PROC(3)
#undef PROC
        }
    }

    float inv = 1.0f / fmaxf(sden, 1e-9f);
    float* op = outf + node * HD + ebase;
    f32x4 r = *(const f32x4*)op;
    f32x4 o;
    o[0] = acc0 * inv + r[0];
    o[1] = acc1 * inv + r[1];
    o[2] = acc2 * inv + r[2];
    o[3] = acc3 * inv + r[3];
    *(f32x4*)op = o;
}

extern "C" void kernel_launch(void* const* d_in, const int* in_sizes, int n_in,
                              void* d_out, int out_size, void* d_ws, size_t ws_size,
                              hipStream_t stream) {
    const void* feat   = d_in[0];
    const int*  src    = (const int*)d_in[1];
    const int*  dst    = (const int*)d_in[2];
    const void* W_fc   = d_in[3];
    const void* W_res  = d_in[4];
    const void* attn_l = d_in[5];
    const void* attn_r = d_in[6];
    float* outf = (float*)d_out;

    char* ws = (char*)d_ws;
    u16*   Wt      = (u16*)(ws + 256);          //  1,048,576 B [1024][512] bf16
    u16*   ft      = (u16*)(ws + 1048832);      // 51,200,000 B [N][512] bf16
    float* el      = (float*)(ws + 52248832);   //  1,600,000 B [N][8]
    float* er      = (float*)(ws + 53848832);   //  1,600,000 B
    int*   deg     = (int*)(ws + 55448832);     //    200,000 B
    int*   rowptr  = (int*)(ws + 55648832);     //    200,064 B (NN+1)
    int*   cursor  = (int*)(ws + 55848896);     //    200,000 B
    int*   csr_src = (int*)(ws + 56048896);     //  3,200,000 B
    u16*   feat16  = (u16*)(ws + 59248896);     // 51,200,000 B (end ~110.5 MB)

    prep_kernel<<<PREP_ZERO, 256, 0, stream>>>(feat, feat16, W_fc, W_res, Wt, deg);
    count_kernel<<<(EE + 255) / 256, 256, 0, stream>>>(dst, deg);
    scan_kernel<<<1, 1024, 0, stream>>>(deg, rowptr, cursor);
    scatter_kernel<<<(EE + 255) / 256, 256, 0, stream>>>(src, dst, cursor, csr_src);

    gemm_kernel<<<NMBLK * 8, 256, 0, stream>>>(feat16, Wt, ft, outf,
                                               attn_l, attn_r, el, er);

    aggregate_kernel<<<(NN + 1) / 2, 256, 0, stream>>>(rowptr, csr_src, ft, el, er, outf);
}

// Round 8
// 653.217 us; speedup vs baseline: 1.0948x; 1.0948x over previous
//
#include <hip/hip_runtime.h>
#include <hip/hip_bf16.h>

#define NN 50000
#define EE 800000
#define INF 512
#define HH 8
#define DD 64
#define HD 512

typedef unsigned short u16;
typedef u16 u16x4 __attribute__((ext_vector_type(4)));
typedef u16 u16x8 __attribute__((ext_vector_type(8)));
typedef __bf16 bf16x8 __attribute__((ext_vector_type(8)));
typedef float f32x4 __attribute__((ext_vector_type(4)));

__device__ __forceinline__ float bf2f(u16 u) {
    return __uint_as_float(((unsigned)u) << 16);
}
__device__ __forceinline__ u16 f2bf(float f) {
    __hip_bfloat16 h = __float2bfloat16(f);
    return *reinterpret_cast<u16*>(&h);
}

// async global->LDS, 16B per lane; LDS dest = wave-uniform base + lane*16
__device__ __forceinline__ void gload_lds16(const void* g, void* l) {
    __builtin_amdgcn_global_load_lds(
        (const __attribute__((address_space(1))) void*)g,
        (__attribute__((address_space(3))) void*)l, 16, 0, 0);
}

// ---- per-block dtype sniff (identical sampling to the original sniff5 kernel:
// u16s at even indices 0..510; uniform data -> uniform verdict across blocks).
__device__ __forceinline__ int sniff_region(const u16* __restrict__ p, int* vote) {
    int tid = threadIdx.x;
    if (tid == 0) *vote = 0;
    __syncthreads();
    float v = fabsf(bf2f(p[2 * tid]));
    if (!(v < 1e4f)) atomicAdd(vote, 1);  // huge / inf / NaN -> looks like f32 guts
    __syncthreads();
    int r = (*vote >= 8) ? 1 : 0;
    __syncthreads();  // protect vote slot before caller reuses the LDS
    return r;
}

// ---- prep (fused): [0,2048) convert feat->bf16 | [2048,2176) transpose W_fc/W_res
//      | [2176,2372) zero deg | [2372,2374) sniff al/ar -> flags.
#define PREP_CONV 2048
#define PREP_TR   (PREP_CONV + 128)
#define PREP_ZERO (PREP_TR + 196)
#define PREP_TOT  (PREP_ZERO + 2)

__global__ __launch_bounds__(256) void prep_kernel(const void* __restrict__ feat,
                                                   u16* __restrict__ feat16,
                                                   const void* __restrict__ W_fc,
                                                   const void* __restrict__ W_res,
                                                   u16* __restrict__ Wt,
                                                   int* __restrict__ deg,
                                                   const void* __restrict__ al,
                                                   const void* __restrict__ ar,
                                                   int* __restrict__ flags) {
    __shared__ u16 tile[64][65];
    const int bid = blockIdx.x;
    const int tid = threadIdx.x;
    if (bid < PREP_CONV) {
        const int isf32 = sniff_region((const u16*)feat, (int*)&tile[0][0]);
        const int total = NN * INF / 8;  // 8 elems per thread
        for (int i = bid * 256 + tid; i < total; i += PREP_CONV * 256) {
            if (isf32) {
                f32x4 a = ((const f32x4*)feat)[2 * i];
                f32x4 b = ((const f32x4*)feat)[2 * i + 1];
                u16x8 w;
#pragma unroll
                for (int j = 0; j < 4; ++j) { w[j] = f2bf(a[j]); w[4 + j] = f2bf(b[j]); }
                ((u16x8*)feat16)[i] = w;
            } else {
                ((u16x8*)feat16)[i] = ((const u16x8*)feat)[i];
            }
        }
    } else if (bid < PREP_TR) {
        const int w = bid - PREP_CONV;           // 0..127
        const void* in = (w < 64) ? W_fc : W_res;
        u16* out = Wt + ((w < 64) ? 0 : 512 * 512);
        const int tb = w & 63;
        const int isf32 = sniff_region((const u16*)in, (int*)&tile[0][0]);
        int tr = (tb & 7) * 64;   // k tile
        int tc = (tb >> 3) * 64;  // col tile
        for (int idx = tid; idx < 64 * 64; idx += 256) {
            int r = idx >> 6, c = idx & 63;
            int g = (tr + r) * 512 + tc + c;
            tile[r][c] = isf32 ? f2bf(((const float*)in)[g]) : ((const u16*)in)[g];
        }
        __syncthreads();
        for (int idx = tid; idx < 64 * 64; idx += 256) {
            int r = idx >> 6, c = idx & 63;
            out[(tc + r) * 512 + tr + c] = tile[c][r];
        }
    } else if (bid < PREP_ZERO) {
        int t = (bid - PREP_TR) * 256 + tid;
        if (t < NN) deg[t] = 0;
    } else {
        const u16* p = (bid == PREP_ZERO) ? (const u16*)al : (const u16*)ar;
        int r = sniff_region(p, (int*)&tile[0][0]);
        if (tid == 0) flags[bid - PREP_ZERO] = r;
    }
}

// ---------------- CSR build: count -> scan -> scatter ----------------
__global__ void count_kernel(const int* __restrict__ dst, int* __restrict__ deg) {
    int e = blockIdx.x * 256 + threadIdx.x;
    if (e < EE) atomicAdd(&deg[dst[e]], 1);
}

#define SCAN_CH 49  // 1024 * 49 = 50176 >= NN
__global__ __launch_bounds__(1024) void scan_kernel(const int* __restrict__ deg,
                                                    int* __restrict__ rowptr,
                                                    int* __restrict__ cursor) {
    __shared__ int sums[1024];
    int t = threadIdx.x;
    int base = t * SCAN_CH;
    int s = 0;
    for (int k = 0; k < SCAN_CH; ++k) {
        int i = base + k;
        if (i < NN) s += deg[i];
    }
    sums[t] = s;
    __syncthreads();
    // Hillis-Steele inclusive scan
    for (int off = 1; off < 1024; off <<= 1) {
        int v = (t >= off) ? sums[t - off] : 0;
        __syncthreads();
        sums[t] += v;
        __syncthreads();
    }
    int run = (t == 0) ? 0 : sums[t - 1];
    for (int k = 0; k < SCAN_CH; ++k) {
        int i = base + k;
        if (i < NN) {
            rowptr[i] = run;
            cursor[i] = run;
            run += deg[i];
        }
    }
    if (t == 0) rowptr[NN] = EE;
}

__global__ void scatter_kernel(const int* __restrict__ src, const int* __restrict__ dst,
                               int* __restrict__ cursor, int* __restrict__ csr_src) {
    int e = blockIdx.x * 256 + threadIdx.x;
    if (e < EE) {
        int p = atomicAdd(&cursor[dst[e]], 1);
        csr_src[p] = src[e];
    }
}

// ---- fused GEMM: [N,512]bf16 @ [512,1024] -> ft (bf16) | residual -> out (f32) ----
// Round-4 version verbatim (best measured: ~135us warm, FETCH 63MB, WRITE 150MB).
// Pure m97 structure: global_load_lds(16B) both operands, 128^2 tile, BK=64,
// single-buffer 32KB LDS -> 5 blocks/CU (TLP hides the per-step vmcnt drain).
// XOR chunk swizzle via pre-swizzled global source (conflict-free, proven r2).
// XCD-bijective block swizzle (proven: FETCH 402MB -> 63MB).
// NOTE r7 lesson: do NOT fold extra epilogues here -- acc[4][4] kept live
// across more code spills to scratch (+250MB traffic, +60us).
#define TM 128
#define TN 128
#define BK 64
#define NT (INF / BK)  // 8
#define NMBLK 392      // 392*128 >= NN, grid 392*8 divisible by 8 XCDs

__global__ __launch_bounds__(256, 5) void gemm_kernel(const u16* __restrict__ Ab,
                                                      const u16* __restrict__ Wt,
                                                      u16* __restrict__ ft,
                                                      float* __restrict__ outf) {
    __shared__ u16 Asm[TM * BK];  // 16KB
    __shared__ u16 Bsm[TN * BK];  // 16KB

    const int bid = blockIdx.x;
    const int r8 = bid & 7;
    const int q = bid >> 3;
    const int m0 = (((q >> 3) << 3) | r8) * TM;
    const int n0 = (q & 7) * TN;
    const int tid = threadIdx.x;
    const int lane = tid & 63;
    const int wave = tid >> 6;
    const int wr = (wave >> 1) * 64;
    const int wc = (wave & 1) * 64;
    const int lrow = lane & 15;
    const int quad = lane >> 4;

    // staging geometry: 1KB group = 8 rows x 128B; lane -> (rg=lane>>3, ch=lane&7)
    const int rg = lane >> 3;
    const int ch = lane & 7;
    const int cs = ch ^ rg;  // pre-swizzled source chunk (row&7 == rg)

    const u16* asrc[4];
    const u16* bsrc[4];
    u16* adst[4];
    u16* bdst[4];
#pragma unroll
    for (int g = 0; g < 4; ++g) {
        int G = wave * 4 + g;
        int r = G * 8 + rg;
        int gr = m0 + r; gr = gr < NN ? gr : NN - 1;   // clamp (dup row harmless)
        asrc[g] = Ab + (size_t)gr * INF + cs * 8;
        bsrc[g] = Wt + (size_t)(n0 + r) * INF + cs * 8;
        adst[g] = Asm + G * 512;
        bdst[g] = Bsm + G * 512;
    }

    f32x4 acc[4][4] = {};

    for (int t = 0; t < NT; ++t) {
        const int k0 = t * BK;
        __syncthreads();  // previous tile's frag reads done before overwrite
#pragma unroll
        for (int g = 0; g < 4; ++g) {
            gload_lds16(asrc[g] + k0, adst[g]);
            gload_lds16(bsrc[g] + k0, bdst[g]);
        }
        __syncthreads();  // vmcnt drain -> tile visible (TLP hides across blocks)

#pragma unroll
        for (int ks = 0; ks < 2; ++ks) {
            bf16x8 af[4], bfr[4];
#pragma unroll
            for (int mi = 0; mi < 4; ++mi) {
                int ar = wr + mi * 16 + lrow;
                int sc = (ks * 4 + quad) ^ (ar & 7);
                u16x8 tv = *(const u16x8*)(Asm + ar * 64 + sc * 8);
                af[mi] = *(bf16x8*)&tv;
            }
#pragma unroll
            for (int ni = 0; ni < 4; ++ni) {
                int br = wc + ni * 16 + lrow;
                int sc = (ks * 4 + quad) ^ (br & 7);
                u16x8 tv = *(const u16x8*)(Bsm + br * 64 + sc * 8);
                bfr[ni] = *(bf16x8*)&tv;
            }
#pragma unroll
            for (int mi = 0; mi < 4; ++mi)
#pragma unroll
                for (int ni = 0; ni < 4; ++ni)
                    acc[mi][ni] = __builtin_amdgcn_mfma_f32_16x16x32_bf16(af[mi], bfr[ni],
                                                                          acc[mi][ni], 0, 0, 0);
        }
    }

    // epilogue: C layout col=lane&15, row=quad*4+reg (m89/m91-verified)
#pragma unroll
    for (int mi = 0; mi < 4; ++mi) {
        int rb = m0 + wr + mi * 16 + quad * 4;
#pragma unroll
        for (int ni = 0; ni < 4; ++ni) {
            int col = n0 + wc + ni * 16 + lrow;
#pragma unroll
            for (int r = 0; r < 4; ++r) {
                int row = rb + r;
                if (row < NN) {
                    float v = acc[mi][ni][r];
                    if (col < HD) ft[row * HD + col] = f2bf(v);
                    else outf[row * HD + (col - HD)] = v;  // residual init of d_out
                }
            }
        }
    }
}

// ---------------- el/er: vectorized attention dots, one wave per node ----------------
__global__ __launch_bounds__(256) void attn_dot_kernel(const u16* __restrict__ ft,
                                                       const void* __restrict__ al,
                                                       const void* __restrict__ ar,
                                                       float* __restrict__ el,
                                                       float* __restrict__ er,
                                                       const int* __restrict__ flags) {
    int node = blockIdx.x * 4 + (threadIdx.x >> 6);
    if (node >= NN) return;
    int lane = threadIdx.x & 63;
    int off = lane * 8;

    float wl[8], wr_[8];
    if (flags[0]) {
        f32x4 a0 = *(const f32x4*)((const float*)al + off);
        f32x4 a1 = *(const f32x4*)((const float*)al + off + 4);
#pragma unroll
        for (int j = 0; j < 4; ++j) { wl[j] = a0[j]; wl[4 + j] = a1[j]; }
    } else {
        u16x8 a = *(const u16x8*)((const u16*)al + off);
#pragma unroll
        for (int j = 0; j < 8; ++j) wl[j] = bf2f(a[j]);
    }
    if (flags[1]) {
        f32x4 a0 = *(const f32x4*)((const float*)ar + off);
        f32x4 a1 = *(const f32x4*)((const float*)ar + off + 4);
#pragma unroll
        for (int j = 0; j < 4; ++j) { wr_[j] = a0[j]; wr_[4 + j] = a1[j]; }
    } else {
        u16x8 a = *(const u16x8*)((const u16*)ar + off);
#pragma unroll
        for (int j = 0; j < 8; ++j) wr_[j] = bf2f(a[j]);
    }

    u16x8 f = *(const u16x8*)(ft + node * HD + off);
    float vl = 0.0f, vr = 0.0f;
#pragma unroll
    for (int j = 0; j < 8; ++j) {
        float x = bf2f(f[j]);
        vl += x * wl[j];
        vr += x * wr_[j];
    }
#pragma unroll
    for (int msk = 1; msk < 8; msk <<= 1) {
        vl += __shfl_xor(vl, msk);
        vr += __shfl_xor(vr, msk);
    }
    if ((lane & 7) == 0) {
        el[node * HH + (lane >> 3)] = vl;
        er[node * HH + (lane >> 3)] = vr;
    }
}

// ---- aggregate (gather): 2 waves per dst node; 4-deep static software pipeline ----
// (round-4 verbatim: best measured 141.9us; 4 structural variants all pinned at
// ~4.1 TB/s -> random-1KB-gather memory-system ceiling for a 51MB table)
// No-max softmax: scale-invariant; v clamped at 75 as overflow insurance.
// All pipeline slots are named registers (rule #20: no runtime indexing).
__global__ __launch_bounds__(256) void aggregate_kernel(const int* __restrict__ rowptr,
                                                        const int* __restrict__ csr_src,
                                                        const u16* __restrict__ ft,
                                                        const float* __restrict__ el,
                                                        const float* __restrict__ er,
                                                        float* __restrict__ outf) {
    int node = blockIdx.x * 2 + (threadIdx.x >> 7);
    if (node >= NN) return;
    int half = (threadIdx.x >> 6) & 1;
    int lane = threadIdx.x & 63;
    int ebase = half * 256 + lane * 4;  // output element offset within [0,512)
    int head = ebase >> 6;              // = half*4 + (lane>>4)
    int beg = rowptr[node], end = rowptr[node + 1];
    float erd = er[node * HH + head];

    float sden = 0.0f;
    float acc0 = 0.f, acc1 = 0.f, acc2 = 0.f, acc3 = 0.f;

    if (beg < end) {
        const int last = end - 1;
        float elp0, elp1, elp2, elp3;
        u16x4 fp0, fp1, fp2, fp3;
        int sn0, sn1, sn2, sn3;
        // prologue: chunk0 srcs -> fill slots; chunk1 srcs into sn*
        {
            int c0 = csr_src[min(beg + 0, last)];
            int c1 = csr_src[min(beg + 1, last)];
            int c2 = csr_src[min(beg + 2, last)];
            int c3 = csr_src[min(beg + 3, last)];
            elp0 = el[c0 * HH + head]; fp0 = *(const u16x4*)(ft + c0 * HD + ebase);
            elp1 = el[c1 * HH + head]; fp1 = *(const u16x4*)(ft + c1 * HD + ebase);
            elp2 = el[c2 * HH + head]; fp2 = *(const u16x4*)(ft + c2 * HD + ebase);
            elp3 = el[c3 * HH + head]; fp3 = *(const u16x4*)(ft + c3 * HD + ebase);
            sn0 = csr_src[min(beg + 4, last)];
            sn1 = csr_src[min(beg + 5, last)];
            sn2 = csr_src[min(beg + 6, last)];
            sn3 = csr_src[min(beg + 7, last)];
        }
        for (int base = beg; base < end; base += 4) {
#define PROC(K)                                                              \
            {                                                                \
                float elv = elp##K;                                          \
                u16x4 f = fp##K;                                             \
                int s = sn##K;                                               \
                elp##K = el[s * HH + head];                                  \
                fp##K = *(const u16x4*)(ft + s * HD + ebase);                \
                sn##K = csr_src[min(base + 8 + K, last)];                    \
                float v = elv + erd;                                         \
                v = v > 0.0f ? v : 0.2f * v;                                 \
                v = fminf(v, 75.0f);                                         \
                float ex = __expf(v);                                        \
                ex = (base + K < end) ? ex : 0.0f;                           \
                sden += ex;                                                  \
                acc0 += bf2f(f[0]) * ex;                                     \
                acc1 += bf2f(f[1]) * ex;                                     \
                acc2 += bf2f(f[2]) * ex;                                     \
                acc3 += bf2f(f[3]) * ex;                                     \
            }
            PROC(0) PROC(1) PROC(2) PROC(3)
#undef PROC
        }
    }

    float inv = 1.0f / fmaxf(sden, 1e-9f);
    float* op = outf + node * HD + ebase;
    f32x4 r = *(const f32x4*)op;
    f32x4 o;
    o[0] = acc0 * inv + r[0];
    o[1] = acc1 * inv + r[1];
    o[2] = acc2 * inv + r[2];
    o[3] = acc3 * inv + r[3];
    *(f32x4*)op = o;
}

extern "C" void kernel_launch(void* const* d_in, const int* in_sizes, int n_in,
                              void* d_out, int out_size, void* d_ws, size_t ws_size,
                              hipStream_t stream) {
    const void* feat   = d_in[0];
    const int*  src    = (const int*)d_in[1];
    const int*  dst    = (const int*)d_in[2];
    const void* W_fc   = d_in[3];
    const void* W_res  = d_in[4];
    const void* attn_l = d_in[5];
    const void* attn_r = d_in[6];
    float* outf = (float*)d_out;

    char* ws = (char*)d_ws;
    int*   flags   = (int*)(ws);                //        256 B [al,ar]
    u16*   Wt      = (u16*)(ws + 256);          //  1,048,576 B [1024][512] bf16
    u16*   ft      = (u16*)(ws + 1048832);      // 51,200,000 B [N][512] bf16
    float* el      = (float*)(ws + 52248832);   //  1,600,000 B [N][8]
    float* er      = (float*)(ws + 53848832);   //  1,600,000 B
    int*   deg     = (int*)(ws + 55448832);     //    200,000 B
    int*   rowptr  = (int*)(ws + 55648832);     //    200,064 B (NN+1)
    int*   cursor  = (int*)(ws + 55848896);     //    200,000 B
    int*   csr_src = (int*)(ws + 56048896);     //  3,200,000 B
    u16*   feat16  = (u16*)(ws + 59248896);     // 51,200,000 B (end ~110.5 MB)

    prep_kernel<<<PREP_TOT, 256, 0, stream>>>(feat, feat16, W_fc, W_res, Wt, deg,
                                              attn_l, attn_r, flags);
    count_kernel<<<(EE + 255) / 256, 256, 0, stream>>>(dst, deg);
    scan_kernel<<<1, 1024, 0, stream>>>(deg, rowptr, cursor);
    scatter_kernel<<<(EE + 255) / 256, 256, 0, stream>>>(src, dst, cursor, csr_src);

    gemm_kernel<<<NMBLK * 8, 256, 0, stream>>>(feat16, Wt, ft, outf);

    attn_dot_kernel<<<(NN + 3) / 4, 256, 0, stream>>>(ft, attn_l, attn_r, el, er, flags);
    aggregate_kernel<<<(NN + 1) / 2, 256, 0, stream>>>(rowptr, csr_src, ft, el, er, outf);
}